// Round 13
// baseline (157.263 us; speedup 1.0000x reference)
//
#include <hip/hip_runtime.h>
#include <math.h>

#define NB 4
#define NN 4096
#define NS 32
#define NTOT (NB*NN*NS)   // 524288
#define FXSCALE 16777216.0   // 2^24 fixed-point scale for deterministic i64 atomics

__device__ __forceinline__ float lrelu(float x){ return x > 0.0f ? x : 0.2f*x; }
__device__ __forceinline__ int symoff(int i, int j){
  return (i<=j) ? (i*(11-i))/2 + j : (j*(11-j))/2 + i;   // 6x6 sym packed index
}
__device__ __forceinline__ void atomic_fx(long long* p, float v){
  long long q = llrint((double)v * FXSCALE);            // double: exact for |v|<2^29
  atomicAdd((unsigned long long*)p, (unsigned long long)q);
}
__device__ __forceinline__ float fx2f(long long q){ return (float)((double)q * (1.0/FXSCALE)); }

// ---------------- K1: ball query, no LDS staging (pts is L1/L2-resident: 48 KB/batch) ----------------
// 1 point per wave, 4096 blocks. Block 0 also zeroes the i64 accumulators.
__global__ __launch_bounds__(256) void k_ballquery(const float* __restrict__ pts, int* __restrict__ idx,
                                                   long long* __restrict__ accs, int n64) {
  if (blockIdx.x == 0) {
    for (int i = threadIdx.x; i < n64; i += 256) accs[i] = 0;
  }
  const int wave = threadIdx.x >> 6;
  const int lane = threadIdx.x & 63;
  const int n = blockIdx.x * 4 + wave;
  const int b = n >> 12, nn = n & (NN-1);
  const float* p = pts + b*3*NN;
  const float cx = p[nn], cy = p[NN+nn], cz = p[2*NN+nn];
  // reference: sq = ((x*x + y*y) + z*z), no contraction
  const float cq = __fadd_rn(__fadd_rn(__fmul_rn(cx,cx), __fmul_rn(cy,cy)), __fmul_rn(cz,cz));
  int* row = idx + ((size_t)n << 5);
  int count = 0;
  int first = 0;
  for (int jb = 0; jb < NN; jb += 64) {
    const int j = jb + lane;
    const float xj = p[j], yj = p[NN+j], zj = p[2*NN+j];
    const float sqj = __fadd_rn(__fadd_rn(__fmul_rn(xj,xj), __fmul_rn(yj,yj)), __fmul_rn(zj,zj));
    // dot via ascending FMA chain (Eigen sgemm K=3 order)
    const float dot = fmaf(zj, cz, fmaf(yj, cy, __fmul_rn(xj, cx)));
    const float r = __fsub_rn(__fadd_rn(cq, sqj), __fmul_rn(2.0f, dot));
    bool valid = !(r > 0.04f);
    unsigned long long m = __ballot(valid);
    if (count == 0 && m != 0ull) first = jb + (int)__builtin_ctzll(m);
    int pos = count + (int)__popcll(m & ((1ull << lane) - 1ull));
    if (valid && pos < NS) row[pos] = j;
    count += (int)__popcll(m);
    if (count >= NS) break;   // count is wave-uniform
  }
  for (int pp = count + lane; pp < NS; pp += 64) row[pp] = first;
}

// ---------------- K2: edge-feature Gram stats -> acc0[8][27] (i64 atomics) ----------------
__global__ __launch_bounds__(256) void k_stats0g(const float* __restrict__ pts, const int* __restrict__ idx,
                                                 long long* __restrict__ acc0) {
  float S[6], M[21];
  #pragma unroll
  for (int i=0;i<6;i++) S[i]=0.f;
  #pragma unroll
  for (int i=0;i<21;i++) M[i]=0.f;
  const int base = blockIdx.x * 1024;
  for (int k=0;k<4;k++){
    const int t = base + k*256 + (int)threadIdx.x;
    const int b = t >> 17;
    const int n = (t >> 5) & (NN-1);
    const int j = idx[t];
    const float* p = pts + b*3*NN;
    float v[6];
    v[0]=p[n]; v[1]=p[NN+n]; v[2]=p[2*NN+n];
    v[3]=p[j]-v[0]; v[4]=p[NN+j]-v[1]; v[5]=p[2*NN+j]-v[2];
    #pragma unroll
    for (int i=0;i<6;i++) S[i] += v[i];
    int c=0;
    #pragma unroll
    for (int i=0;i<6;i++)
      #pragma unroll
      for (int jj=i;jj<6;jj++){ M[c] = fmaf(v[i], v[jj], M[c]); c++; }
  }
  #pragma unroll
  for (int off=32; off>=1; off>>=1){
    #pragma unroll
    for (int i=0;i<6;i++)  S[i] += __shfl_xor(S[i], off);
    #pragma unroll
    for (int i=0;i<21;i++) M[i] += __shfl_xor(M[i], off);
  }
  __shared__ float red[4][27];
  const int wave = threadIdx.x >> 6, lane = threadIdx.x & 63;
  if (lane == 0){
    #pragma unroll
    for (int i=0;i<6;i++)  red[wave][i]   = S[i];
    #pragma unroll
    for (int i=0;i<21;i++) red[wave][6+i] = M[i];
  }
  __syncthreads();
  if (threadIdx.x < 27){
    float a = red[0][threadIdx.x]+red[1][threadIdx.x]+red[2][threadIdx.x]+red[3][threadIdx.x];
    atomic_fx(&acc0[(blockIdx.x & 7)*27 + threadIdx.x], a);
  }
}

// ---------------- finalize bn0 from Gram accumulators ----------------
__global__ __launch_bounds__(256) void k_fin0g(const long long* __restrict__ acc0,
    const float* __restrict__ w0, const float* __restrict__ b0,
    const float* __restrict__ g0, const float* __restrict__ be0, float* __restrict__ bn0) {
  __shared__ float SM[27];
  if (threadIdx.x < 27){
    long long s = 0;
    #pragma unroll
    for (int k=0;k<8;k++) s += acc0[k*27 + threadIdx.x];
    SM[threadIdx.x] = fx2f(s);
  }
  __syncthreads();
  if (threadIdx.x < 32){
    const int cch = threadIdx.x;
    float w[6];
    #pragma unroll
    for (int i=0;i<6;i++) w[i] = w0[cch*6+i];
    float dot=0.f;
    #pragma unroll
    for (int i=0;i<6;i++) dot = fmaf(w[i], SM[i], dot);
    float qd=0.f;
    #pragma unroll
    for (int i=0;i<6;i++){
      float ti=0.f;
      #pragma unroll
      for (int j=0;j<6;j++) ti = fmaf(w[j], SM[6+symoff(i,j)], ti);
      qd = fmaf(w[i], ti, qd);
    }
    const float NT = (float)NTOT;
    const float bb = b0[cch];
    float s1 = dot + NT*bb;
    float s2 = qd + 2.f*bb*dot + NT*bb*bb;
    const float inv = 1.0f / NT;
    float mean = s1 * inv;
    float var  = fmaxf(s2*inv - mean*mean, 0.0f);
    float sc = g0[cch] / sqrtf(var + 1e-5f);
    bn0[cch] = sc;
    bn0[32+cch] = be0[cch] - mean*sc;
  }
}

// ---------------- generic finalize: acc[NCOPY][2C] i64 -> scale/shift ----------------
__global__ __launch_bounds__(256) void k_fin(const long long* __restrict__ acc, int ncopy, int C,
    const float* __restrict__ g, const float* __restrict__ beta, float* __restrict__ bn) {
  if ((int)threadIdx.x < C) {
    const int c = threadIdx.x;
    long long ts = 0, tq = 0;
    for (int k=0;k<ncopy;k++){ ts += acc[k*2*C + c]; tq += acc[k*2*C + C + c]; }
    const float inv = 1.0f / (float)NTOT;
    float m = fx2f(ts) * inv;
    float var = fmaxf(fx2f(tq)*inv - m*m, 0.0f);
    float sc = g[c] / sqrtf(var + 1e-5f);
    bn[c] = sc;
    bn[C+c] = beta[c] - m*sc;
  }
}

// ---------------- shared: compute h0[32] = lrelu(bn0(l0(edge))) for row t ----------------
__device__ __forceinline__ void compute_h0(const float* __restrict__ pts, const int* __restrict__ idx,
    const float* __restrict__ w0, const float* __restrict__ b0, const float* __restrict__ bn0,
    int t, float* __restrict__ h0) {
  const int b = t >> 17;
  const int n = (t >> 5) & (NN-1);
  const int j = idx[t];
  const float* p = pts + b*3*NN;
  const float cx = p[n], cy = p[NN+n], cz = p[2*NN+n];
  const float e3 = p[j]-cx, e4 = p[NN+j]-cy, e5 = p[2*NN+j]-cz;
  #pragma unroll
  for (int c=0;c<32;c++){
    float v = b0[c];
    v = fmaf(cx, w0[c*6+0], v);
    v = fmaf(cy, w0[c*6+1], v);
    v = fmaf(cz, w0[c*6+2], v);
    v = fmaf(e3, w0[c*6+3], v);
    v = fmaf(e4, w0[c*6+4], v);
    v = fmaf(e5, w0[c*6+5], v);
    h0[c] = lrelu(fmaf(v, bn0[c], bn0[32+c]));
  }
}

// ---------------- K3: layer1 stats by recompute. XOR-swizzled st: exactly 32768 B ----------------
__global__ __launch_bounds__(256) void k_stats1r(const float* __restrict__ pts, const int* __restrict__ idx,
    const float* __restrict__ w0, const float* __restrict__ b0, const float* __restrict__ bn0,
    const float* __restrict__ w1, const float* __restrict__ b1, long long* __restrict__ acc1) {
  __shared__ float st[8192];
  const int tid = threadIdx.x;
  const int t = blockIdx.x * 256 + tid;
  float h0[32];
  compute_h0(pts, idx, w0, b0, bn0, t, h0);
  const int sw = tid & 31;
  #pragma unroll
  for (int og=0; og<8; ++og){
    float a0=b1[4*og+0], a1=b1[4*og+1], a2=b1[4*og+2], a3=b1[4*og+3];
    #pragma unroll
    for (int c=0;c<32;c++){
      a0 = fmaf(h0[c], w1[(4*og+0)*32+c], a0);
      a1 = fmaf(h0[c], w1[(4*og+1)*32+c], a1);
      a2 = fmaf(h0[c], w1[(4*og+2)*32+c], a2);
      a3 = fmaf(h0[c], w1[(4*og+3)*32+c], a3);
    }
    st[tid*32 + ((4*og+0) ^ sw)] = a0;
    st[tid*32 + ((4*og+1) ^ sw)] = a1;
    st[tid*32 + ((4*og+2) ^ sw)] = a2;
    st[tid*32 + ((4*og+3) ^ sw)] = a3;
  }
  __syncthreads();
  const int ch = tid & 31, grp = tid >> 5;
  float s = 0.f, q = 0.f;
  #pragma unroll
  for (int r=0;r<32;r++){
    float v = st[(grp*32 + r)*32 + (ch ^ r)];
    s += v; q = fmaf(v,v,q);
  }
  __syncthreads();
  st[grp*64 + ch] = s;
  st[grp*64 + 32 + ch] = q;
  __syncthreads();
  if (tid < 64){
    const int c = tid & 31, half = tid >> 5;
    float acc = 0.f;
    #pragma unroll
    for (int g2=0; g2<8; ++g2) acc += st[g2*64 + half*32 + c];
    atomic_fx(&acc1[(blockIdx.x & 7)*64 + half*32 + c], acc);
  }
}

// ---------------- K4: recompute l0+l1, bn1+lrelu -> LDS h; layer2 with WAVE-UNIFORM channels ----
// Phase 2: wave w owns channels [16w,16w+16) (scalar s_load weights, one SGPR/FMA);
// lane = (point p = lane>>3, row-group rgrp = lane&7), 4 rows each, 8x fewer LDS instrs.
// PSTR = 32*36+4 = 1156 words (== 4 mod 32): min-conflict for both phases; 16B-aligned.
#define RSTR 36
#define PSTR 1156
__global__ __launch_bounds__(256) void k_l2all(const float* __restrict__ pts, const int* __restrict__ idx,
    const float* __restrict__ w0, const float* __restrict__ b0, const float* __restrict__ bn0,
    const float* __restrict__ w1, const float* __restrict__ b1, const float* __restrict__ bn1,
    const float* __restrict__ w2, const float* __restrict__ b2,
    float* __restrict__ pmax, long long* __restrict__ acc2) {
  __shared__ float h[8*PSTR];   // 36992 B
  const int tid = threadIdx.x;
  const int t = blockIdx.x * 256 + tid;
  {
    float h0[32];
    compute_h0(pts, idx, w0, b0, bn0, t, h0);
    const int p_ = tid >> 5, s_ = tid & 31;
    float* dst = h + p_*PSTR + s_*RSTR;
    #pragma unroll
    for (int og=0; og<8; ++og){
      float a0=b1[4*og+0], a1=b1[4*og+1], a2=b1[4*og+2], a3=b1[4*og+3];
      #pragma unroll
      for (int c=0;c<32;c++){
        a0 = fmaf(h0[c], w1[(4*og+0)*32+c], a0);
        a1 = fmaf(h0[c], w1[(4*og+1)*32+c], a1);
        a2 = fmaf(h0[c], w1[(4*og+2)*32+c], a2);
        a3 = fmaf(h0[c], w1[(4*og+3)*32+c], a3);
      }
      float4 hv;
      hv.x = lrelu(fmaf(a0, bn1[4*og+0], bn1[32+4*og+0]));
      hv.y = lrelu(fmaf(a1, bn1[4*og+1], bn1[32+4*og+1]));
      hv.z = lrelu(fmaf(a2, bn1[4*og+2], bn1[32+4*og+2]));
      hv.w = lrelu(fmaf(a3, bn1[4*og+3], bn1[32+4*og+3]));
      *(float4*)(dst + 4*og) = hv;
    }
  }
  __syncthreads();
  // ---- phase 2 ----
  const int lane = tid & 63;
  const int p = lane >> 3, rgrp = lane & 7;
  const int ch0 = __builtin_amdgcn_readfirstlane((tid >> 6) * 16);   // wave-uniform channel base
  const float* hp = h + p*PSTR + rgrp*4*RSTR;
  float sum[16], sq[16], mx[16];
  #pragma unroll
  for (int k=0;k<16;k++){ sum[k]=0.f; sq[k]=0.f; mx[k]=-3.0e38f; }
  #pragma unroll
  for (int r=0;r<4;r++){
    float row[32];
    #pragma unroll
    for (int i=0;i<8;i++) *(float4*)(row+4*i) = *(const float4*)(hp + r*RSTR + 4*i);
    #pragma unroll
    for (int k=0;k<16;k++){
      const float* wk = w2 + (ch0+k)*32;   // scalar (s_load) weights
      float a = b2[ch0+k];
      #pragma unroll
      for (int c=0;c<32;c++) a = fmaf(row[c], wk[c], a);
      sum[k] += a; sq[k] = fmaf(a,a,sq[k]); mx[k] = fmaxf(mx[k], a);
    }
  }
  // reduce over the 8 rgrp lanes of each point
  #pragma unroll
  for (int off=1; off<8; off<<=1){
    #pragma unroll
    for (int k=0;k<16;k++){
      sum[k] += __shfl_xor(sum[k], off);
      sq[k]  += __shfl_xor(sq[k],  off);
      mx[k]   = fmaxf(mx[k], __shfl_xor(mx[k], off));
    }
  }
  if (rgrp == 0){
    float* pm = pmax + (size_t)(blockIdx.x*8 + p)*64 + ch0;
    #pragma unroll
    for (int k=0;k<4;k++)
      *(float4*)(pm + 4*k) = make_float4(mx[4*k], mx[4*k+1], mx[4*k+2], mx[4*k+3]);
  }
  __syncthreads();
  if (rgrp == 0){
    #pragma unroll
    for (int k=0;k<16;k++){
      h[p*128 + ch0 + k] = sum[k];
      h[p*128 + 64 + ch0 + k] = sq[k];
    }
  }
  __syncthreads();
  if (tid < 128){
    const int o = tid & 63, half = tid >> 6;
    float acc = 0.f;
    #pragma unroll
    for (int pp=0;pp<8;pp++) acc += h[pp*128 + half*64 + o];
    atomic_fx(&acc2[(blockIdx.x & 15)*128 + half*64 + o], acc);
  }
}

// ---------------- K6: bn2 + lrelu on per-point maxes, transposed write to out (B,64,N) ----------------
__global__ __launch_bounds__(256) void k_out(const float* __restrict__ pmax, const float* __restrict__ bn2,
                                             float* __restrict__ out) {
  __shared__ float sm[64*65];   // [ch][pt]
  const int tid = threadIdx.x;
  const int p0 = blockIdx.x * 64;              // 64 points per block, all within one batch
  const int ptl = tid >> 2, quad = tid & 3;
  const float* src = pmax + (size_t)(p0 + ptl)*64 + quad*16;
  #pragma unroll
  for (int k=0;k<4;k++){
    const float4 v = *(const float4*)(src + k*4);
    const int ch = quad*16 + k*4;
    sm[(ch+0)*65 + ptl] = v.x;
    sm[(ch+1)*65 + ptl] = v.y;
    sm[(ch+2)*65 + ptl] = v.z;
    sm[(ch+3)*65 + ptl] = v.w;
  }
  __syncthreads();
  const int b = p0 >> 12, n0 = p0 & (NN-1);
  #pragma unroll
  for (int i=0;i<4;i++){
    const int j = tid + i*256;
    const int ch = j >> 4, f4 = j & 15;
    const float sc = bn2[ch], sh = bn2[64+ch];
    float4 v;
    v.x = lrelu(fmaf(sm[ch*65 + f4*4+0], sc, sh));
    v.y = lrelu(fmaf(sm[ch*65 + f4*4+1], sc, sh));
    v.z = lrelu(fmaf(sm[ch*65 + f4*4+2], sc, sh));
    v.w = lrelu(fmaf(sm[ch*65 + f4*4+3], sc, sh));
    *(float4*)(out + (size_t)(b*64 + ch)*NN + n0 + f4*4) = v;
  }
}

extern "C" void kernel_launch(void* const* d_in, const int* in_sizes, int n_in,
                              void* d_out, int out_size, void* d_ws, size_t ws_size,
                              hipStream_t stream) {
  const float* pts = (const float*)d_in[0];
  const float* w0  = (const float*)d_in[1];
  const float* b0  = (const float*)d_in[2];
  const float* g0  = (const float*)d_in[3];
  const float* be0 = (const float*)d_in[4];
  const float* w1  = (const float*)d_in[5];
  const float* b1  = (const float*)d_in[6];
  const float* g1  = (const float*)d_in[7];
  const float* be1 = (const float*)d_in[8];
  const float* w2  = (const float*)d_in[9];
  const float* b2  = (const float*)d_in[10];
  const float* g2  = (const float*)d_in[11];
  const float* be2 = (const float*)d_in[12];
  float* out = (float*)d_out;

  char* ws = (char*)d_ws;
  int*       idx  = (int*)      (ws + 0);          // 2 MB
  float*     pmax = (float*)    (ws + 2097152);    // 16384*64*4 = 4 MB
  long long* acc0 = (long long*)(ws + 6291456);    // 8*27*8 = 1728 B (pad 2048)
  long long* acc1 = (long long*)(ws + 6293504);    // 8*64*8 = 4096 B
  long long* acc2 = (long long*)(ws + 6297600);    // 16*128*8 = 16384 B
  float*     bn0  = (float*)    (ws + 6313984);
  float*     bn1  = (float*)    (ws + 6314240);
  float*     bn2  = (float*)    (ws + 6314496);

  k_ballquery<<<4096, 256, 0, stream>>>(pts, idx, acc0, 2816);  // block 0 zeroes acc0..acc2
  k_stats0g <<<512,  256, 0, stream>>>(pts, idx, acc0);
  k_fin0g   <<<1,    256, 0, stream>>>(acc0, w0, b0, g0, be0, bn0);
  k_stats1r <<<2048, 256, 0, stream>>>(pts, idx, w0, b0, bn0, w1, b1, acc1);
  k_fin     <<<1,    256, 0, stream>>>(acc1, 8, 32, g1, be1, bn1);
  k_l2all   <<<2048, 256, 0, stream>>>(pts, idx, w0, b0, bn0, w1, b1, bn1, w2, b2, pmax, acc2);
  k_fin     <<<1,    256, 0, stream>>>(acc2, 16, 64, g2, be2, bn2);
  k_out     <<<256,  256, 0, stream>>>(pmax, bn2, out);
}

// Round 14
// 136.658 us; speedup vs baseline: 1.1508x; 1.1508x over previous
//
#include <hip/hip_runtime.h>
#include <math.h>

#define NB 4
#define NN 4096
#define NS 32
#define NTOT (NB*NN*NS)   // 524288
#define FXSCALE 16777216.0   // 2^24 fixed-point scale for deterministic i64 atomics

__device__ __forceinline__ float lrelu(float x){ return x > 0.0f ? x : 0.2f*x; }
__device__ __forceinline__ int symoff(int i, int j){
  return (i<=j) ? (i*(11-i))/2 + j : (j*(11-j))/2 + i;   // 6x6 sym packed index
}
__device__ __forceinline__ void atomic_fx(long long* p, float v){
  long long q = llrint((double)v * FXSCALE);            // double: exact for |v|<2^29
  atomicAdd((unsigned long long*)p, (unsigned long long)q);
}
__device__ __forceinline__ float fx2f(long long q){ return (float)((double)q * (1.0/FXSCALE)); }

// ---------------- K1: ball query, no LDS staging (pts is L1/L2-resident: 48 KB/batch) ----------------
// 1 point per wave, 4096 blocks. Block 0 also zeroes the i64 accumulators.
__global__ __launch_bounds__(256) void k_ballquery(const float* __restrict__ pts, int* __restrict__ idx,
                                                   long long* __restrict__ accs, int n64) {
  if (blockIdx.x == 0) {
    for (int i = threadIdx.x; i < n64; i += 256) accs[i] = 0;
  }
  const int wave = threadIdx.x >> 6;
  const int lane = threadIdx.x & 63;
  const int n = blockIdx.x * 4 + wave;
  const int b = n >> 12, nn = n & (NN-1);
  const float* p = pts + b*3*NN;
  const float cx = p[nn], cy = p[NN+nn], cz = p[2*NN+nn];
  // reference: sq = ((x*x + y*y) + z*z), no contraction
  const float cq = __fadd_rn(__fadd_rn(__fmul_rn(cx,cx), __fmul_rn(cy,cy)), __fmul_rn(cz,cz));
  int* row = idx + ((size_t)n << 5);
  int count = 0;
  int first = 0;
  for (int jb = 0; jb < NN; jb += 64) {
    const int j = jb + lane;
    const float xj = p[j], yj = p[NN+j], zj = p[2*NN+j];
    const float sqj = __fadd_rn(__fadd_rn(__fmul_rn(xj,xj), __fmul_rn(yj,yj)), __fmul_rn(zj,zj));
    // dot via ascending FMA chain (Eigen sgemm K=3 order)
    const float dot = fmaf(zj, cz, fmaf(yj, cy, __fmul_rn(xj, cx)));
    const float r = __fsub_rn(__fadd_rn(cq, sqj), __fmul_rn(2.0f, dot));
    bool valid = !(r > 0.04f);
    unsigned long long m = __ballot(valid);
    if (count == 0 && m != 0ull) first = jb + (int)__builtin_ctzll(m);
    int pos = count + (int)__popcll(m & ((1ull << lane) - 1ull));
    if (valid && pos < NS) row[pos] = j;
    count += (int)__popcll(m);
    if (count >= NS) break;   // count is wave-uniform
  }
  for (int pp = count + lane; pp < NS; pp += 64) row[pp] = first;
}

// ---------------- K2: edge-feature Gram stats -> acc0[8][27] (i64 atomics) ----------------
__global__ __launch_bounds__(256) void k_stats0g(const float* __restrict__ pts, const int* __restrict__ idx,
                                                 long long* __restrict__ acc0) {
  float S[6], M[21];
  #pragma unroll
  for (int i=0;i<6;i++) S[i]=0.f;
  #pragma unroll
  for (int i=0;i<21;i++) M[i]=0.f;
  const int base = blockIdx.x * 1024;
  for (int k=0;k<4;k++){
    const int t = base + k*256 + (int)threadIdx.x;
    const int b = t >> 17;
    const int n = (t >> 5) & (NN-1);
    const int j = idx[t];
    const float* p = pts + b*3*NN;
    float v[6];
    v[0]=p[n]; v[1]=p[NN+n]; v[2]=p[2*NN+n];
    v[3]=p[j]-v[0]; v[4]=p[NN+j]-v[1]; v[5]=p[2*NN+j]-v[2];
    #pragma unroll
    for (int i=0;i<6;i++) S[i] += v[i];
    int c=0;
    #pragma unroll
    for (int i=0;i<6;i++)
      #pragma unroll
      for (int jj=i;jj<6;jj++){ M[c] = fmaf(v[i], v[jj], M[c]); c++; }
  }
  #pragma unroll
  for (int off=32; off>=1; off>>=1){
    #pragma unroll
    for (int i=0;i<6;i++)  S[i] += __shfl_xor(S[i], off);
    #pragma unroll
    for (int i=0;i<21;i++) M[i] += __shfl_xor(M[i], off);
  }
  __shared__ float red[4][27];
  const int wave = threadIdx.x >> 6, lane = threadIdx.x & 63;
  if (lane == 0){
    #pragma unroll
    for (int i=0;i<6;i++)  red[wave][i]   = S[i];
    #pragma unroll
    for (int i=0;i<21;i++) red[wave][6+i] = M[i];
  }
  __syncthreads();
  if (threadIdx.x < 27){
    float a = red[0][threadIdx.x]+red[1][threadIdx.x]+red[2][threadIdx.x]+red[3][threadIdx.x];
    atomic_fx(&acc0[(blockIdx.x & 7)*27 + threadIdx.x], a);
  }
}

// ---------------- finalize bn0 from Gram accumulators ----------------
__global__ __launch_bounds__(256) void k_fin0g(const long long* __restrict__ acc0,
    const float* __restrict__ w0, const float* __restrict__ b0,
    const float* __restrict__ g0, const float* __restrict__ be0, float* __restrict__ bn0) {
  __shared__ float SM[27];
  if (threadIdx.x < 27){
    long long s = 0;
    #pragma unroll
    for (int k=0;k<8;k++) s += acc0[k*27 + threadIdx.x];
    SM[threadIdx.x] = fx2f(s);
  }
  __syncthreads();
  if (threadIdx.x < 32){
    const int cch = threadIdx.x;
    float w[6];
    #pragma unroll
    for (int i=0;i<6;i++) w[i] = w0[cch*6+i];
    float dot=0.f;
    #pragma unroll
    for (int i=0;i<6;i++) dot = fmaf(w[i], SM[i], dot);
    float qd=0.f;
    #pragma unroll
    for (int i=0;i<6;i++){
      float ti=0.f;
      #pragma unroll
      for (int j=0;j<6;j++) ti = fmaf(w[j], SM[6+symoff(i,j)], ti);
      qd = fmaf(w[i], ti, qd);
    }
    const float NT = (float)NTOT;
    const float bb = b0[cch];
    float s1 = dot + NT*bb;
    float s2 = qd + 2.f*bb*dot + NT*bb*bb;
    const float inv = 1.0f / NT;
    float mean = s1 * inv;
    float var  = fmaxf(s2*inv - mean*mean, 0.0f);
    float sc = g0[cch] / sqrtf(var + 1e-5f);
    bn0[cch] = sc;
    bn0[32+cch] = be0[cch] - mean*sc;
  }
}

// ---------------- generic finalize: acc[NCOPY][2C] i64 -> scale/shift ----------------
__global__ __launch_bounds__(256) void k_fin(const long long* __restrict__ acc, int ncopy, int C,
    const float* __restrict__ g, const float* __restrict__ beta, float* __restrict__ bn) {
  if ((int)threadIdx.x < C) {
    const int c = threadIdx.x;
    long long ts = 0, tq = 0;
    for (int k=0;k<ncopy;k++){ ts += acc[k*2*C + c]; tq += acc[k*2*C + C + c]; }
    const float inv = 1.0f / (float)NTOT;
    float m = fx2f(ts) * inv;
    float var = fmaxf(fx2f(tq)*inv - m*m, 0.0f);
    float sc = g[c] / sqrtf(var + 1e-5f);
    bn[c] = sc;
    bn[C+c] = beta[c] - m*sc;
  }
}

// ---------------- shared: compute h0[32] = lrelu(bn0(l0(edge))) for row t ----------------
__device__ __forceinline__ void compute_h0(const float* __restrict__ pts, const int* __restrict__ idx,
    const float* __restrict__ w0, const float* __restrict__ b0, const float* __restrict__ bn0,
    int t, float* __restrict__ h0) {
  const int b = t >> 17;
  const int n = (t >> 5) & (NN-1);
  const int j = idx[t];
  const float* p = pts + b*3*NN;
  const float cx = p[n], cy = p[NN+n], cz = p[2*NN+n];
  const float e3 = p[j]-cx, e4 = p[NN+j]-cy, e5 = p[2*NN+j]-cz;
  #pragma unroll
  for (int c=0;c<32;c++){
    float v = b0[c];
    v = fmaf(cx, w0[c*6+0], v);
    v = fmaf(cy, w0[c*6+1], v);
    v = fmaf(cz, w0[c*6+2], v);
    v = fmaf(e3, w0[c*6+3], v);
    v = fmaf(e4, w0[c*6+4], v);
    v = fmaf(e5, w0[c*6+5], v);
    h0[c] = lrelu(fmaf(v, bn0[c], bn0[32+c]));
  }
}

// ---------------- K3: layer1 stats by recompute. XOR-swizzled st: exactly 32768 B ----------------
__global__ __launch_bounds__(256) void k_stats1r(const float* __restrict__ pts, const int* __restrict__ idx,
    const float* __restrict__ w0, const float* __restrict__ b0, const float* __restrict__ bn0,
    const float* __restrict__ w1, const float* __restrict__ b1, long long* __restrict__ acc1) {
  __shared__ float st[8192];
  const int tid = threadIdx.x;
  const int t = blockIdx.x * 256 + tid;
  float h0[32];
  compute_h0(pts, idx, w0, b0, bn0, t, h0);
  const int sw = tid & 31;
  #pragma unroll
  for (int og=0; og<8; ++og){
    float a0=b1[4*og+0], a1=b1[4*og+1], a2=b1[4*og+2], a3=b1[4*og+3];
    #pragma unroll
    for (int c=0;c<32;c++){
      a0 = fmaf(h0[c], w1[(4*og+0)*32+c], a0);
      a1 = fmaf(h0[c], w1[(4*og+1)*32+c], a1);
      a2 = fmaf(h0[c], w1[(4*og+2)*32+c], a2);
      a3 = fmaf(h0[c], w1[(4*og+3)*32+c], a3);
    }
    st[tid*32 + ((4*og+0) ^ sw)] = a0;
    st[tid*32 + ((4*og+1) ^ sw)] = a1;
    st[tid*32 + ((4*og+2) ^ sw)] = a2;
    st[tid*32 + ((4*og+3) ^ sw)] = a3;
  }
  __syncthreads();
  const int ch = tid & 31, grp = tid >> 5;
  float s = 0.f, q = 0.f;
  #pragma unroll
  for (int r=0;r<32;r++){
    float v = st[(grp*32 + r)*32 + (ch ^ r)];
    s += v; q = fmaf(v,v,q);
  }
  __syncthreads();
  st[grp*64 + ch] = s;
  st[grp*64 + 32 + ch] = q;
  __syncthreads();
  if (tid < 64){
    const int c = tid & 31, half = tid >> 5;
    float acc = 0.f;
    #pragma unroll
    for (int g2=0; g2<8; ++g2) acc += st[g2*64 + half*32 + c];
    atomic_fx(&acc1[(blockIdx.x & 7)*64 + half*32 + c], acc);
  }
}

// ---------------- K4: 4-point blocks (128 rows), LDS 18.7 KB -> 8 blocks/CU, 32 waves/CU ----------
// Phase 1: thread = (row r=tid&127, ch-half hh=tid>>7, wave-uniform via readfirstlane -> w1 s_load).
// Phase 2: R8-proven per-thread structure: (p=tid>>6, rh=(tid>>5)&1, q=tid&31), 16 rows each,
//          shfl_xor(32) combines the rh halves. RSTR=36 (144 B, 16B-aligned - R10's bug avoided).
#define RSTR 36
#define PSTR 1168   // 32*36 + 16 stagger; 4672 B, 16B-aligned
__global__ __launch_bounds__(256) void k_l2all(const float* __restrict__ pts, const int* __restrict__ idx,
    const float* __restrict__ w0, const float* __restrict__ b0, const float* __restrict__ bn0,
    const float* __restrict__ w1, const float* __restrict__ b1, const float* __restrict__ bn1,
    const float* __restrict__ w2, const float* __restrict__ b2,
    float* __restrict__ pmax, long long* __restrict__ acc2) {
  __shared__ float h[4*PSTR];   // 18688 B
  const int tid = threadIdx.x;
  // ---- phase 1 ----
  {
    const int r = tid & 127;
    const int hh = __builtin_amdgcn_readfirstlane(tid >> 7);   // wave-uniform channel half
    const int t = blockIdx.x * 128 + r;
    float h0[32];
    compute_h0(pts, idx, w0, b0, bn0, t, h0);
    const int p_ = r >> 5, rl = r & 31;
    float* dst = h + p_*PSTR + rl*RSTR + hh*16;
    #pragma unroll
    for (int og=0; og<4; ++og){
      const int c0 = hh*16 + 4*og;
      float a0=b1[c0+0], a1=b1[c0+1], a2=b1[c0+2], a3=b1[c0+3];
      #pragma unroll
      for (int c=0;c<32;c++){
        a0 = fmaf(h0[c], w1[(c0+0)*32+c], a0);
        a1 = fmaf(h0[c], w1[(c0+1)*32+c], a1);
        a2 = fmaf(h0[c], w1[(c0+2)*32+c], a2);
        a3 = fmaf(h0[c], w1[(c0+3)*32+c], a3);
      }
      float4 hv;
      hv.x = lrelu(fmaf(a0, bn1[c0+0], bn1[32+c0+0]));
      hv.y = lrelu(fmaf(a1, bn1[c0+1], bn1[32+c0+1]));
      hv.z = lrelu(fmaf(a2, bn1[c0+2], bn1[32+c0+2]));
      hv.w = lrelu(fmaf(a3, bn1[c0+3], bn1[32+c0+3]));
      *(float4*)(dst + 4*og) = hv;
    }
  }
  __syncthreads();
  // ---- phase 2 (R8 structure, 16 rows/thread) ----
  const int q = tid & 31;
  const int rh = (tid >> 5) & 1;
  const int p = tid >> 6;
  const int o0 = 2*q, o1 = 2*q+1;
  float wa[32], wb[32];
  #pragma unroll
  for (int i=0;i<8;i++){
    const float4 A = *(const float4*)(w2 + o0*32 + i*4);
    wa[4*i+0]=A.x; wa[4*i+1]=A.y; wa[4*i+2]=A.z; wa[4*i+3]=A.w;
    const float4 B = *(const float4*)(w2 + o1*32 + i*4);
    wb[4*i+0]=B.x; wb[4*i+1]=B.y; wb[4*i+2]=B.z; wb[4*i+3]=B.w;
  }
  const float bb0 = b2[o0], bb1 = b2[o1];
  float s0=0.f, s1=0.f, q0=0.f, q1=0.f;
  float m0 = -3.0e38f, m1 = -3.0e38f;
  const float* hp = h + p*PSTR + rh*(16*RSTR);
  for (int s=0;s<16;s++){
    const float* row = hp + s*RSTR;
    float a0=bb0, a1=bb1;
    #pragma unroll
    for (int i=0;i<8;i++){
      const float4 hv = *(const float4*)(row + 4*i);
      a0 = fmaf(hv.x, wa[4*i+0], a0); a0 = fmaf(hv.y, wa[4*i+1], a0);
      a0 = fmaf(hv.z, wa[4*i+2], a0); a0 = fmaf(hv.w, wa[4*i+3], a0);
      a1 = fmaf(hv.x, wb[4*i+0], a1); a1 = fmaf(hv.y, wb[4*i+1], a1);
      a1 = fmaf(hv.z, wb[4*i+2], a1); a1 = fmaf(hv.w, wb[4*i+3], a1);
    }
    s0 += a0; q0 = fmaf(a0,a0,q0); m0 = fmaxf(m0, a0);
    s1 += a1; q1 = fmaf(a1,a1,q1); m1 = fmaxf(m1, a1);
  }
  // combine the two row-halves (lanes 32 apart within the wave)
  s0 += __shfl_xor(s0, 32);  s1 += __shfl_xor(s1, 32);
  q0 += __shfl_xor(q0, 32);  q1 += __shfl_xor(q1, 32);
  m0 = fmaxf(m0, __shfl_xor(m0, 32));
  m1 = fmaxf(m1, __shfl_xor(m1, 32));
  if (rh == 0){
    float* pm = pmax + (size_t)(blockIdx.x*4 + p)*64;
    pm[o0] = m0; pm[o1] = m1;
  }
  __syncthreads();
  if (rh == 0){
    h[p*128 + o0] = s0;  h[p*128 + o1] = s1;
    h[512 + p*128 + o0] = q0;  h[512 + p*128 + o1] = q1;   // note: sq block at +512
  }
  __syncthreads();
  if (tid < 128){
    const int o = tid & 63, half = tid >> 6;
    float acc = 0.f;
    #pragma unroll
    for (int pp=0;pp<4;pp++) acc += h[half*512 + pp*128 + o];
    atomic_fx(&acc2[(blockIdx.x & 31)*128 + half*64 + o], acc);
  }
}

// ---------------- K6: bn2 + lrelu on per-point maxes, transposed write to out (B,64,N) ----------------
__global__ __launch_bounds__(256) void k_out(const float* __restrict__ pmax, const float* __restrict__ bn2,
                                             float* __restrict__ out) {
  __shared__ float sm[64*65];   // [ch][pt]
  const int tid = threadIdx.x;
  const int p0 = blockIdx.x * 64;              // 64 points per block, all within one batch
  const int ptl = tid >> 2, quad = tid & 3;
  const float* src = pmax + (size_t)(p0 + ptl)*64 + quad*16;
  #pragma unroll
  for (int k=0;k<4;k++){
    const float4 v = *(const float4*)(src + k*4);
    const int ch = quad*16 + k*4;
    sm[(ch+0)*65 + ptl] = v.x;
    sm[(ch+1)*65 + ptl] = v.y;
    sm[(ch+2)*65 + ptl] = v.z;
    sm[(ch+3)*65 + ptl] = v.w;
  }
  __syncthreads();
  const int b = p0 >> 12, n0 = p0 & (NN-1);
  #pragma unroll
  for (int i=0;i<4;i++){
    const int j = tid + i*256;
    const int ch = j >> 4, f4 = j & 15;
    const float sc = bn2[ch], sh = bn2[64+ch];
    float4 v;
    v.x = lrelu(fmaf(sm[ch*65 + f4*4+0], sc, sh));
    v.y = lrelu(fmaf(sm[ch*65 + f4*4+1], sc, sh));
    v.z = lrelu(fmaf(sm[ch*65 + f4*4+2], sc, sh));
    v.w = lrelu(fmaf(sm[ch*65 + f4*4+3], sc, sh));
    *(float4*)(out + (size_t)(b*64 + ch)*NN + n0 + f4*4) = v;
  }
}

extern "C" void kernel_launch(void* const* d_in, const int* in_sizes, int n_in,
                              void* d_out, int out_size, void* d_ws, size_t ws_size,
                              hipStream_t stream) {
  const float* pts = (const float*)d_in[0];
  const float* w0  = (const float*)d_in[1];
  const float* b0  = (const float*)d_in[2];
  const float* g0  = (const float*)d_in[3];
  const float* be0 = (const float*)d_in[4];
  const float* w1  = (const float*)d_in[5];
  const float* b1  = (const float*)d_in[6];
  const float* g1  = (const float*)d_in[7];
  const float* be1 = (const float*)d_in[8];
  const float* w2  = (const float*)d_in[9];
  const float* b2  = (const float*)d_in[10];
  const float* g2  = (const float*)d_in[11];
  const float* be2 = (const float*)d_in[12];
  float* out = (float*)d_out;

  char* ws = (char*)d_ws;
  int*       idx  = (int*)      (ws + 0);          // 2 MB
  float*     pmax = (float*)    (ws + 2097152);    // 16384*64*4 = 4 MB
  long long* acc0 = (long long*)(ws + 6291456);    // 8*27*8 = 1728 B (pad 2048)
  long long* acc1 = (long long*)(ws + 6293504);    // 8*64*8 = 4096 B
  long long* acc2 = (long long*)(ws + 6297600);    // 32*128*8 = 32768 B
  float*     bn0  = (float*)    (ws + 6330368);
  float*     bn1  = (float*)    (ws + 6330624);
  float*     bn2  = (float*)    (ws + 6330880);

  k_ballquery<<<4096, 256, 0, stream>>>(pts, idx, acc0, 4864);  // block 0 zeroes acc0..acc2
  k_stats0g <<<512,  256, 0, stream>>>(pts, idx, acc0);
  k_fin0g   <<<1,    256, 0, stream>>>(acc0, w0, b0, g0, be0, bn0);
  k_stats1r <<<2048, 256, 0, stream>>>(pts, idx, w0, b0, bn0, w1, b1, acc1);
  k_fin     <<<1,    256, 0, stream>>>(acc1, 8, 32, g1, be1, bn1);
  k_l2all   <<<4096, 256, 0, stream>>>(pts, idx, w0, b0, bn0, w1, b1, bn1, w2, b2, pmax, acc2);
  k_fin     <<<1,    256, 0, stream>>>(acc2, 32, 64, g2, be2, bn2);
  k_out     <<<256,  256, 0, stream>>>(pmax, bn2, out);
}

// Round 15
// 118.487 us; speedup vs baseline: 1.3273x; 1.1534x over previous
//
#include <hip/hip_runtime.h>
#include <math.h>

#define NB 4
#define NN 4096
#define NS 32
#define NTOT (NB*NN*NS)   // 524288
#define FXSCALE 16777216.0   // 2^24 fixed-point scale for deterministic i64 atomics

__device__ __forceinline__ float lrelu(float x){ return x > 0.0f ? x : 0.2f*x; }
__device__ __forceinline__ int symoff(int i, int j){
  return (i<=j) ? (i*(11-i))/2 + j : (j*(11-j))/2 + i;   // 6x6 sym packed index
}
__device__ __forceinline__ void atomic_fx(long long* p, float v){
  long long q = llrint((double)v * FXSCALE);            // double: exact for |v|<2^29
  atomicAdd((unsigned long long*)p, (unsigned long long)q);
}
__device__ __forceinline__ float fx2f(long long q){ return (float)((double)q * (1.0/FXSCALE)); }

// ---- in-block BN finalizers (every block recomputes identically from i64 accs: deterministic) ----
__device__ __forceinline__ void block_bn0(const long long* __restrict__ acc0,
    const float* __restrict__ w0, const float* __restrict__ b0,
    const float* __restrict__ g0, const float* __restrict__ be0,
    float* __restrict__ sm27, float* __restrict__ bn0l) {
  if (threadIdx.x < 27){
    long long s = 0;
    #pragma unroll
    for (int k=0;k<8;k++) s += acc0[k*27 + threadIdx.x];
    sm27[threadIdx.x] = fx2f(s);
  }
  __syncthreads();
  if (threadIdx.x < 32){
    const int cch = threadIdx.x;
    float w[6];
    #pragma unroll
    for (int i=0;i<6;i++) w[i] = w0[cch*6+i];
    float dot=0.f;
    #pragma unroll
    for (int i=0;i<6;i++) dot = fmaf(w[i], sm27[i], dot);
    float qd=0.f;
    #pragma unroll
    for (int i=0;i<6;i++){
      float ti=0.f;
      #pragma unroll
      for (int j=0;j<6;j++) ti = fmaf(w[j], sm27[6+symoff(i,j)], ti);
      qd = fmaf(w[i], ti, qd);
    }
    const float NT = (float)NTOT;
    const float bb = b0[cch];
    float s1 = dot + NT*bb;
    float s2 = qd + 2.f*bb*dot + NT*bb*bb;
    const float inv = 1.0f / NT;
    float mean = s1 * inv;
    float var  = fmaxf(s2*inv - mean*mean, 0.0f);
    float sc = g0[cch] / sqrtf(var + 1e-5f);
    bn0l[cch] = sc;
    bn0l[32+cch] = be0[cch] - mean*sc;
  }
  __syncthreads();
}

__device__ __forceinline__ void block_bn1(const long long* __restrict__ acc1,
    const float* __restrict__ g1, const float* __restrict__ be1, float* __restrict__ bn1l) {
  if (threadIdx.x < 32){
    const int c = threadIdx.x;
    long long ts = 0, tq = 0;
    #pragma unroll
    for (int k=0;k<8;k++){ ts += acc1[k*64 + c]; tq += acc1[k*64 + 32 + c]; }
    const float inv = 1.0f / (float)NTOT;
    float m = fx2f(ts) * inv;
    float var = fmaxf(fx2f(tq)*inv - m*m, 0.0f);
    float sc = g1[c] / sqrtf(var + 1e-5f);
    bn1l[c] = sc;
    bn1l[32+c] = be1[c] - m*sc;
  }
  __syncthreads();
}

// ---------------- K1: ball query, no LDS staging (pts is L1/L2-resident: 48 KB/batch) ----------------
// 1 point per wave, 4096 blocks. Block 0 also zeroes the i64 accumulators.
__global__ __launch_bounds__(256) void k_ballquery(const float* __restrict__ pts, int* __restrict__ idx,
                                                   long long* __restrict__ accs, int n64) {
  if (blockIdx.x == 0) {
    for (int i = threadIdx.x; i < n64; i += 256) accs[i] = 0;
  }
  const int wave = threadIdx.x >> 6;
  const int lane = threadIdx.x & 63;
  const int n = blockIdx.x * 4 + wave;
  const int b = n >> 12, nn = n & (NN-1);
  const float* p = pts + b*3*NN;
  const float cx = p[nn], cy = p[NN+nn], cz = p[2*NN+nn];
  // reference: sq = ((x*x + y*y) + z*z), no contraction
  const float cq = __fadd_rn(__fadd_rn(__fmul_rn(cx,cx), __fmul_rn(cy,cy)), __fmul_rn(cz,cz));
  int* row = idx + ((size_t)n << 5);
  int count = 0;
  int first = 0;
  for (int jb = 0; jb < NN; jb += 64) {
    const int j = jb + lane;
    const float xj = p[j], yj = p[NN+j], zj = p[2*NN+j];
    const float sqj = __fadd_rn(__fadd_rn(__fmul_rn(xj,xj), __fmul_rn(yj,yj)), __fmul_rn(zj,zj));
    // dot via ascending FMA chain (Eigen sgemm K=3 order)
    const float dot = fmaf(zj, cz, fmaf(yj, cy, __fmul_rn(xj, cx)));
    const float r = __fsub_rn(__fadd_rn(cq, sqj), __fmul_rn(2.0f, dot));
    bool valid = !(r > 0.04f);
    unsigned long long m = __ballot(valid);
    if (count == 0 && m != 0ull) first = jb + (int)__builtin_ctzll(m);
    int pos = count + (int)__popcll(m & ((1ull << lane) - 1ull));
    if (valid && pos < NS) row[pos] = j;
    count += (int)__popcll(m);
    if (count >= NS) break;   // count is wave-uniform
  }
  for (int pp = count + lane; pp < NS; pp += 64) row[pp] = first;
}

// ---------------- K2: edge-feature Gram stats -> acc0[8][27] (i64 atomics) ----------------
__global__ __launch_bounds__(256) void k_stats0g(const float* __restrict__ pts, const int* __restrict__ idx,
                                                 long long* __restrict__ acc0) {
  float S[6], M[21];
  #pragma unroll
  for (int i=0;i<6;i++) S[i]=0.f;
  #pragma unroll
  for (int i=0;i<21;i++) M[i]=0.f;
  const int base = blockIdx.x * 1024;
  for (int k=0;k<4;k++){
    const int t = base + k*256 + (int)threadIdx.x;
    const int b = t >> 17;
    const int n = (t >> 5) & (NN-1);
    const int j = idx[t];
    const float* p = pts + b*3*NN;
    float v[6];
    v[0]=p[n]; v[1]=p[NN+n]; v[2]=p[2*NN+n];
    v[3]=p[j]-v[0]; v[4]=p[NN+j]-v[1]; v[5]=p[2*NN+j]-v[2];
    #pragma unroll
    for (int i=0;i<6;i++) S[i] += v[i];
    int c=0;
    #pragma unroll
    for (int i=0;i<6;i++)
      #pragma unroll
      for (int jj=i;jj<6;jj++){ M[c] = fmaf(v[i], v[jj], M[c]); c++; }
  }
  #pragma unroll
  for (int off=32; off>=1; off>>=1){
    #pragma unroll
    for (int i=0;i<6;i++)  S[i] += __shfl_xor(S[i], off);
    #pragma unroll
    for (int i=0;i<21;i++) M[i] += __shfl_xor(M[i], off);
  }
  __shared__ float red[4][27];
  const int wave = threadIdx.x >> 6, lane = threadIdx.x & 63;
  if (lane == 0){
    #pragma unroll
    for (int i=0;i<6;i++)  red[wave][i]   = S[i];
    #pragma unroll
    for (int i=0;i<21;i++) red[wave][6+i] = M[i];
  }
  __syncthreads();
  if (threadIdx.x < 27){
    float a = red[0][threadIdx.x]+red[1][threadIdx.x]+red[2][threadIdx.x]+red[3][threadIdx.x];
    atomic_fx(&acc0[(blockIdx.x & 7)*27 + threadIdx.x], a);
  }
}

// ---------------- shared: compute h0[32] = lrelu(bn0(l0(edge))) for row t ----------------
__device__ __forceinline__ void compute_h0(const float* __restrict__ pts, const int* __restrict__ idx,
    const float* __restrict__ w0, const float* __restrict__ b0, const float* __restrict__ bn0,
    int t, float* __restrict__ h0) {
  const int b = t >> 17;
  const int n = (t >> 5) & (NN-1);
  const int j = idx[t];
  const float* p = pts + b*3*NN;
  const float cx = p[n], cy = p[NN+n], cz = p[2*NN+n];
  const float e3 = p[j]-cx, e4 = p[NN+j]-cy, e5 = p[2*NN+j]-cz;
  #pragma unroll
  for (int c=0;c<32;c++){
    float v = b0[c];
    v = fmaf(cx, w0[c*6+0], v);
    v = fmaf(cy, w0[c*6+1], v);
    v = fmaf(cz, w0[c*6+2], v);
    v = fmaf(e3, w0[c*6+3], v);
    v = fmaf(e4, w0[c*6+4], v);
    v = fmaf(e5, w0[c*6+5], v);
    h0[c] = lrelu(fmaf(v, bn0[c], bn0[32+c]));
  }
}

// ---------------- K3: layer1 stats by recompute (bn0 finalized in-block) ----------------
// XOR-swizzled st: element (ch,row) at row*32 + (ch^row): per-instruction banks distinct both phases.
__global__ __launch_bounds__(256) void k_stats1r(const float* __restrict__ pts, const int* __restrict__ idx,
    const float* __restrict__ w0, const float* __restrict__ b0,
    const float* __restrict__ g0, const float* __restrict__ be0,
    const float* __restrict__ w1, const float* __restrict__ b1,
    const long long* __restrict__ acc0, long long* __restrict__ acc1) {
  __shared__ float st[8192];
  __shared__ float sm27[27];
  __shared__ float bn0l[64];
  block_bn0(acc0, w0, b0, g0, be0, sm27, bn0l);
  const int tid = threadIdx.x;
  const int t = blockIdx.x * 256 + tid;
  float h0[32];
  compute_h0(pts, idx, w0, b0, bn0l, t, h0);
  const int sw = tid & 31;
  #pragma unroll
  for (int og=0; og<8; ++og){
    float a0=b1[4*og+0], a1=b1[4*og+1], a2=b1[4*og+2], a3=b1[4*og+3];
    #pragma unroll
    for (int c=0;c<32;c++){
      a0 = fmaf(h0[c], w1[(4*og+0)*32+c], a0);
      a1 = fmaf(h0[c], w1[(4*og+1)*32+c], a1);
      a2 = fmaf(h0[c], w1[(4*og+2)*32+c], a2);
      a3 = fmaf(h0[c], w1[(4*og+3)*32+c], a3);
    }
    st[tid*32 + ((4*og+0) ^ sw)] = a0;
    st[tid*32 + ((4*og+1) ^ sw)] = a1;
    st[tid*32 + ((4*og+2) ^ sw)] = a2;
    st[tid*32 + ((4*og+3) ^ sw)] = a3;
  }
  __syncthreads();
  const int ch = tid & 31, grp = tid >> 5;
  float s = 0.f, q = 0.f;
  #pragma unroll
  for (int r=0;r<32;r++){
    float v = st[(grp*32 + r)*32 + (ch ^ r)];
    s += v; q = fmaf(v,v,q);
  }
  __syncthreads();
  st[grp*64 + ch] = s;
  st[grp*64 + 32 + ch] = q;
  __syncthreads();
  if (tid < 64){
    const int c = tid & 31, half = tid >> 5;
    float acc = 0.f;
    #pragma unroll
    for (int g2=0; g2<8; ++g2) acc += st[g2*64 + half*32 + c];
    atomic_fx(&acc1[(blockIdx.x & 7)*64 + half*32 + c], acc);
  }
}

// ---------------- K4: recompute l0+l1, bn1+lrelu -> LDS h, layer2 stats + pre-bn2 max ----------------
// bn0/bn1 finalized in-block. R8-proven structure; pmax stored as float2 (full-sector writes).
#define PSTRIDE 1160
__global__ __launch_bounds__(256,3) void k_l2all(const float* __restrict__ pts, const int* __restrict__ idx,
    const float* __restrict__ w0, const float* __restrict__ b0,
    const float* __restrict__ g0, const float* __restrict__ be0,
    const float* __restrict__ w1, const float* __restrict__ b1,
    const float* __restrict__ g1, const float* __restrict__ be1,
    const float* __restrict__ w2, const float* __restrict__ b2,
    const long long* __restrict__ acc0, const long long* __restrict__ acc1,
    float* __restrict__ pmax, long long* __restrict__ acc2) {
  __shared__ float h[8*PSTRIDE];
  __shared__ float sm27[27];
  __shared__ float bn0l[64];
  __shared__ float bn1l[64];
  block_bn0(acc0, w0, b0, g0, be0, sm27, bn0l);
  block_bn1(acc1, g1, be1, bn1l);
  const int tid = threadIdx.x;
  const int t = blockIdx.x * 256 + tid;
  {
    float h0[32];
    compute_h0(pts, idx, w0, b0, bn0l, t, h0);
    const int p_ = tid >> 5, s_ = tid & 31;
    float* dst = h + p_*PSTRIDE + s_*36;
    #pragma unroll
    for (int og=0; og<8; ++og){
      float a0=b1[4*og+0], a1=b1[4*og+1], a2=b1[4*og+2], a3=b1[4*og+3];
      #pragma unroll
      for (int c=0;c<32;c++){
        a0 = fmaf(h0[c], w1[(4*og+0)*32+c], a0);
        a1 = fmaf(h0[c], w1[(4*og+1)*32+c], a1);
        a2 = fmaf(h0[c], w1[(4*og+2)*32+c], a2);
        a3 = fmaf(h0[c], w1[(4*og+3)*32+c], a3);
      }
      float4 hv;
      hv.x = lrelu(fmaf(a0, bn1l[4*og+0], bn1l[32+4*og+0]));
      hv.y = lrelu(fmaf(a1, bn1l[4*og+1], bn1l[32+4*og+1]));
      hv.z = lrelu(fmaf(a2, bn1l[4*og+2], bn1l[32+4*og+2]));
      hv.w = lrelu(fmaf(a3, bn1l[4*og+3], bn1l[32+4*og+3]));
      *(float4*)(dst + 4*og) = hv;
    }
  }
  __syncthreads();
  const int q = tid & 31, p = tid >> 5;
  const int o0 = 2*q, o1 = 2*q+1;
  float wa[32], wb[32];
  #pragma unroll
  for (int i=0;i<8;i++){
    const float4 A = *(const float4*)(w2 + o0*32 + i*4);
    wa[4*i+0]=A.x; wa[4*i+1]=A.y; wa[4*i+2]=A.z; wa[4*i+3]=A.w;
    const float4 B = *(const float4*)(w2 + o1*32 + i*4);
    wb[4*i+0]=B.x; wb[4*i+1]=B.y; wb[4*i+2]=B.z; wb[4*i+3]=B.w;
  }
  const float bb0 = b2[o0], bb1 = b2[o1];
  float s0=0.f, s1=0.f, q0=0.f, q1=0.f;
  float m0 = -3.0e38f, m1 = -3.0e38f;
  const float* hp = h + p*PSTRIDE;
  for (int s=0;s<32;s++){
    const float* row = hp + s*36;
    float a0=bb0, a1=bb1;
    #pragma unroll
    for (int i=0;i<8;i++){
      const float4 hv = *(const float4*)(row + 4*i);
      a0 = fmaf(hv.x, wa[4*i+0], a0); a0 = fmaf(hv.y, wa[4*i+1], a0);
      a0 = fmaf(hv.z, wa[4*i+2], a0); a0 = fmaf(hv.w, wa[4*i+3], a0);
      a1 = fmaf(hv.x, wb[4*i+0], a1); a1 = fmaf(hv.y, wb[4*i+1], a1);
      a1 = fmaf(hv.z, wb[4*i+2], a1); a1 = fmaf(hv.w, wb[4*i+3], a1);
    }
    s0 += a0; q0 = fmaf(a0,a0,q0); m0 = fmaxf(m0, a0);
    s1 += a1; q1 = fmaf(a1,a1,q1); m1 = fmaxf(m1, a1);
  }
  float* pm = pmax + (size_t)(blockIdx.x*8 + p)*64;
  *(float2*)(pm + o0) = make_float2(m0, m1);   // contiguous 8B/lane -> full sectors
  __syncthreads();
  h[p*64+o0] = s0; h[p*64+o1] = s1;
  h[512 + p*64+o0] = q0; h[512 + p*64+o1] = q1;
  __syncthreads();
  if (tid < 128){
    const int o = tid & 63, half = tid >> 6;
    float acc = 0.f;
    #pragma unroll
    for (int pp=0;pp<8;pp++) acc += h[half*512 + pp*64 + o];
    atomic_fx(&acc2[(blockIdx.x & 15)*128 + half*64 + o], acc);
  }
}

// ---------------- K5: bn2 (finalized in-block) + lrelu on maxes, transposed write (B,64,N) ----------------
__global__ __launch_bounds__(256) void k_out(const float* __restrict__ pmax,
    const long long* __restrict__ acc2, const float* __restrict__ g2, const float* __restrict__ be2,
    float* __restrict__ out) {
  __shared__ float sm[64*65];   // [ch][pt]
  __shared__ float bn2l[128];
  const int tid = threadIdx.x;
  if (tid < 64){
    long long ts = 0, tq = 0;
    #pragma unroll
    for (int k=0;k<16;k++){ ts += acc2[k*128 + tid]; tq += acc2[k*128 + 64 + tid]; }
    const float inv = 1.0f / (float)NTOT;
    float m = fx2f(ts) * inv;
    float var = fmaxf(fx2f(tq)*inv - m*m, 0.0f);
    float sc = g2[tid] / sqrtf(var + 1e-5f);
    bn2l[tid] = sc;
    bn2l[64+tid] = be2[tid] - m*sc;
  }
  const int p0 = blockIdx.x * 64;              // 64 points per block, all within one batch
  const int ptl = tid >> 2, quad = tid & 3;
  const float* src = pmax + (size_t)(p0 + ptl)*64 + quad*16;
  #pragma unroll
  for (int k=0;k<4;k++){
    const float4 v = *(const float4*)(src + k*4);
    const int ch = quad*16 + k*4;
    sm[(ch+0)*65 + ptl] = v.x;
    sm[(ch+1)*65 + ptl] = v.y;
    sm[(ch+2)*65 + ptl] = v.z;
    sm[(ch+3)*65 + ptl] = v.w;
  }
  __syncthreads();
  const int b = p0 >> 12, n0 = p0 & (NN-1);
  #pragma unroll
  for (int i=0;i<4;i++){
    const int j = tid + i*256;
    const int ch = j >> 4, f4 = j & 15;
    const float sc = bn2l[ch], sh = bn2l[64+ch];
    float4 v;
    v.x = lrelu(fmaf(sm[ch*65 + f4*4+0], sc, sh));
    v.y = lrelu(fmaf(sm[ch*65 + f4*4+1], sc, sh));
    v.z = lrelu(fmaf(sm[ch*65 + f4*4+2], sc, sh));
    v.w = lrelu(fmaf(sm[ch*65 + f4*4+3], sc, sh));
    *(float4*)(out + (size_t)(b*64 + ch)*NN + n0 + f4*4) = v;
  }
}

extern "C" void kernel_launch(void* const* d_in, const int* in_sizes, int n_in,
                              void* d_out, int out_size, void* d_ws, size_t ws_size,
                              hipStream_t stream) {
  const float* pts = (const float*)d_in[0];
  const float* w0  = (const float*)d_in[1];
  const float* b0  = (const float*)d_in[2];
  const float* g0  = (const float*)d_in[3];
  const float* be0 = (const float*)d_in[4];
  const float* w1  = (const float*)d_in[5];
  const float* b1  = (const float*)d_in[6];
  const float* g1  = (const float*)d_in[7];
  const float* be1 = (const float*)d_in[8];
  const float* w2  = (const float*)d_in[9];
  const float* b2  = (const float*)d_in[10];
  const float* g2  = (const float*)d_in[11];
  const float* be2 = (const float*)d_in[12];
  float* out = (float*)d_out;

  char* ws = (char*)d_ws;
  int*       idx  = (int*)      (ws + 0);          // 2 MB
  float*     pmax = (float*)    (ws + 2097152);    // 16384*64*4 = 4 MB
  long long* acc0 = (long long*)(ws + 6291456);    // 8*27*8 = 1728 B (pad 2048)
  long long* acc1 = (long long*)(ws + 6293504);    // 8*64*8 = 4096 B
  long long* acc2 = (long long*)(ws + 6297600);    // 16*128*8 = 16384 B

  k_ballquery<<<4096, 256, 0, stream>>>(pts, idx, acc0, 2816);  // block 0 zeroes acc0..acc2
  k_stats0g  <<<512,  256, 0, stream>>>(pts, idx, acc0);
  k_stats1r  <<<2048, 256, 0, stream>>>(pts, idx, w0, b0, g0, be0, w1, b1, acc0, acc1);
  k_l2all    <<<2048, 256, 0, stream>>>(pts, idx, w0, b0, g0, be0, w1, b1, g1, be1, w2, b2,
                                        acc0, acc1, pmax, acc2);
  k_out      <<<256,  256, 0, stream>>>(pmax, acc2, g2, be2, out);
}